// Round 3
// baseline (251.236 us; speedup 1.0000x reference)
//
#include <hip/hip_runtime.h>
#include <hip/hip_cooperative_groups.h>
#include <cstdint>
#include <cstddef>

namespace cg = cooperative_groups;

// Problem constants: W is [COUT, CIN]; x is [4*4096, CIN]. All I/O fp32.
#define CIN  1024
#define COUT 1024

typedef __attribute__((ext_vector_type(8))) short bf16x8;
typedef __attribute__((ext_vector_type(4))) float f32x4;

// ---------- fp32 -> bf16 (round-to-nearest-even) ----------
__device__ __forceinline__ unsigned short f2bf(float f) {
    union { float f; unsigned int i; } v;
    v.f = f;
    unsigned int u = v.i;
    u += 0x7FFFu + ((u >> 16) & 1u);
    return (unsigned short)(u >> 16);
}

__device__ __forceinline__ void cvt8(const float* __restrict__ s,
                                     unsigned short* __restrict__ d) {
    float4 v0 = *(const float4*)s;
    float4 v1 = *(const float4*)(s + 4);
    union { bf16x8 v; unsigned short u[8]; } w;
    w.u[0] = f2bf(v0.x); w.u[1] = f2bf(v0.y); w.u[2] = f2bf(v0.z); w.u[3] = f2bf(v0.w);
    w.u[4] = f2bf(v1.x); w.u[5] = f2bf(v1.y); w.u[6] = f2bf(v1.z); w.u[7] = f2bf(v1.w);
    *(bf16x8*)d = w.v;
}

// ================= fused cooperative kernel =================
// One launch replaces {zero, scatter, cvt_W, cvt_x, gemm}; the ~90us of
// inter-kernel launch overhead (total was gemm + 114us constant across rounds,
// vs ~20us of real side-kernel work) is the target.
//
// Grid: (M/256)*(COUT/256) = 64*4 = 256 blocks x 512 thr. 128 KiB LDS forces
// 1 block/CU, so 256 blocks == 256 CUs: cooperative residency is exact.
//
// Phase 3 GEMM = round-2 v2 schedule, unchanged (BK=64, 2-buf, 8 phases/2
// K-tiles, fragment persistence, even 2-gload/phase staging, vmcnt(4)
// checkpoints at p4/p8; chunk-XOR LDS swizzle, 0 bank conflicts measured).

#define GLD16(SRC_, DST_)                                                     \
  __builtin_amdgcn_global_load_lds(                                           \
      (const __attribute__((address_space(1))) void*)(SRC_),                  \
      (__attribute__((address_space(3))) void*)(DST_), 16, 0, 0)

#define STAGE_A(BUF_, HALF_, KT_) do {                                        \
    GLD16(pa + (size_t)((HALF_) * 128)      * CIN + (size_t)(KT_) * 64,       \
          As + (BUF_) * 16384 + ((HALF_) * 128) * 64 + tid8);                 \
    GLD16(pa + (size_t)((HALF_) * 128 + 64) * CIN + (size_t)(KT_) * 64,       \
          As + (BUF_) * 16384 + ((HALF_) * 128 + 64) * 64 + tid8);            \
  } while (0)

#define STAGE_B(BUF_, HALF_, KT_) do {                                        \
    GLD16(pb + (size_t)((HALF_) * 128)      * CIN + (size_t)(KT_) * 64,       \
          Bs + (BUF_) * 16384 + ((HALF_) * 128) * 64 + tid8);                 \
    GLD16(pb + (size_t)((HALF_) * 128 + 64) * CIN + (size_t)(KT_) * 64,       \
          Bs + (BUF_) * 16384 + ((HALF_) * 128 + 64) * 64 + tid8);            \
  } while (0)

#define LOAD_A(BUF_, QA_) do {                                                \
    const unsigned short* ab_ = As + (BUF_) * 16384 + ((QA_) * 128 + wm64) * 64; \
    _Pragma("unroll")                                                         \
    for (int ks_ = 0; ks_ < 2; ++ks_) {                                       \
      const int cx_ = ((ks_ * 4 + quad) ^ s7) * 8;                            \
      _Pragma("unroll")                                                       \
      for (int mf_ = 0; mf_ < 4; ++mf_)                                       \
        af[ks_][mf_] = *(const bf16x8*)(ab_ + (mf_ * 16 + l16) * 64 + cx_);   \
    }                                                                         \
  } while (0)

#define LOAD_B(BUF_, QB_, DST_) do {                                          \
    const unsigned short* bb_ = Bs + (BUF_) * 16384 + ((QB_) * 128 + wn32) * 64; \
    _Pragma("unroll")                                                         \
    for (int ks_ = 0; ks_ < 2; ++ks_) {                                       \
      const int cx_ = ((ks_ * 4 + quad) ^ s7) * 8;                            \
      _Pragma("unroll")                                                       \
      for (int nf_ = 0; nf_ < 2; ++nf_)                                       \
        DST_[ks_][nf_] = *(const bf16x8*)(bb_ + (nf_ * 16 + l16) * 64 + cx_); \
    }                                                                         \
  } while (0)

#define MFMA_Q(QA_, QB_, BF_)                                                 \
    _Pragma("unroll")                                                         \
    for (int ks_ = 0; ks_ < 2; ++ks_)                                         \
      _Pragma("unroll")                                                       \
      for (int mf_ = 0; mf_ < 4; ++mf_)                                       \
        _Pragma("unroll")                                                     \
        for (int nf_ = 0; nf_ < 2; ++nf_)                                     \
          acc[QA_][QB_][mf_][nf_] = __builtin_amdgcn_mfma_f32_16x16x32_bf16(  \
              af[ks_][mf_], BF_[ks_][nf_], acc[QA_][QB_][mf_][nf_], 0, 0, 0)

#define SYNC_PRE() do {                                                       \
    __builtin_amdgcn_s_barrier();                                             \
    asm volatile("s_waitcnt lgkmcnt(0)" ::: "memory");                        \
    __builtin_amdgcn_sched_barrier(0);                                        \
    __builtin_amdgcn_s_setprio(1);                                            \
  } while (0)

#define SYNC_POST() __builtin_amdgcn_s_setprio(0)

__global__ __launch_bounds__(512, 2) void fused_all(
    const float* __restrict__ x,        // [M, CIN] fp32
    const float* __restrict__ vals,     // [nnz]
    const int* __restrict__ rows,       // [nnz]
    const int* __restrict__ cols,       // [nnz]
    float* __restrict__ Wf,             // ws: [COUT, CIN] fp32
    unsigned short* __restrict__ Wb,    // ws: [COUT, CIN] bf16
    unsigned short* __restrict__ Xb,    // ws: [M, CIN] bf16
    float* __restrict__ C,              // [M, COUT] fp32
    int M, int nnz) {
    cg::grid_group grid = cg::this_grid();

    const int tid = threadIdx.x;
    const unsigned gtid = blockIdx.x * 512u + (unsigned)tid;
    const unsigned gsz  = gridDim.x * 512u;

    // ---- phase 0: zero Wf (independent) + cvt x -> bf16 ----
    for (unsigned i = gtid; i < COUT * CIN / 4; i += gsz)
        ((float4*)Wf)[i] = float4{0.f, 0.f, 0.f, 0.f};
    const size_t xchunks = (size_t)M * CIN / 8;
    for (size_t i = gtid; i < xchunks; i += gsz)
        cvt8(x + i * 8, Xb + i * 8);
    grid.sync();

    // ---- phase 1: scatter-add duplicates like coalesce() ----
    for (unsigned i = gtid; i < (unsigned)nnz; i += gsz)
        atomicAdd(Wf + (size_t)rows[i] * CIN + cols[i], vals[i]);
    grid.sync();

    // ---- phase 2: W -> bf16 ----
    for (unsigned i = gtid; i < COUT * CIN / 8; i += gsz)
        cvt8(Wf + (size_t)i * 8, Wb + (size_t)i * 8);
    grid.sync();

    // ---- phase 3: 256x256 8-phase GEMM, out = x @ W^T ----
    constexpr int K = CIN;
    __shared__ __align__(16) unsigned short As[2 * 16384];  // 2 x [256][64]
    __shared__ __align__(16) unsigned short Bs[2 * 16384];

    const int nbx  = M / 256;            // 64
    const int bx   = (int)blockIdx.x % nbx;
    const int by   = (int)blockIdx.x / nbx;
    const int lane = tid & 63;
    const int w    = tid >> 6;
    const int quad = lane >> 4;
    const int l16  = lane & 15;
    const int s7   = l16 & 7;
    const int wm64 = (w >> 2) * 64;
    const int wn32 = (w & 3) * 32;

    const int rowA0 = bx * 256;
    const int rowB0 = by * 256;

    const int stg_row = tid >> 3;
    const int c_data  = (tid & 7) ^ (stg_row & 7);
    const int tid8    = tid * 8;
    const unsigned short* pa = Xb + (size_t)(rowA0 + stg_row) * K + c_data * 8;
    const unsigned short* pb = Wb + (size_t)(rowB0 + stg_row) * K + c_data * 8;

    f32x4 acc[2][2][4][2] = {};

    // prologue: tile0 -> buf0 (A0,B0,B1,A1), tile1 -> buf1 (A0,B0)
    STAGE_A(0, 0, 0); STAGE_B(0, 0, 0); STAGE_B(0, 1, 0); STAGE_A(0, 1, 0);
    STAGE_A(1, 0, 1); STAGE_B(1, 0, 1);
    asm volatile("s_waitcnt vmcnt(4)" ::: "memory");  // tile0 complete
    __builtin_amdgcn_s_barrier();

#pragma unroll 1
    for (int i = 0; i < 8; ++i) {          // 16 K-tiles of 64, 2 per iteration
        const int  k1 = 2 * i + 1;
        const int  k2 = 2 * i + 2;
        const int  k3 = 2 * i + 3;
        const bool nl = (i < 7);

        bf16x8 af[2][4];                   // A-frags, reused 2 phases
        bf16x8 bf0[2][2], bf1[2][2];       // B-frags, persist whole K-tile

        // even tile (buf0): quadrants (0,0)(0,1)(1,0)(1,1)
        LOAD_A(0, 0); LOAD_B(0, 0, bf0);
        STAGE_B(1, 1, k1);
        SYNC_PRE(); MFMA_Q(0, 0, bf0); SYNC_POST();
        __builtin_amdgcn_s_barrier();

        LOAD_B(0, 1, bf1);
        STAGE_A(1, 1, k1);
        SYNC_PRE(); MFMA_Q(0, 1, bf1); SYNC_POST();
        __builtin_amdgcn_s_barrier();

        LOAD_A(0, 1);
        if (nl) STAGE_A(0, 0, k2);
        SYNC_PRE(); MFMA_Q(1, 0, bf0); SYNC_POST();
        __builtin_amdgcn_s_barrier();

        if (nl) STAGE_B(0, 0, k2);
        SYNC_PRE(); MFMA_Q(1, 1, bf1); SYNC_POST();
        if (nl) { asm volatile("s_waitcnt vmcnt(4)" ::: "memory"); }   // K1
        else    { asm volatile("s_waitcnt vmcnt(0)" ::: "memory"); }
        __builtin_amdgcn_s_barrier();

        // odd tile (buf1)
        LOAD_A(1, 0); LOAD_B(1, 0, bf0);
        if (nl) STAGE_B(0, 1, k2);
        SYNC_PRE(); MFMA_Q(0, 0, bf0); SYNC_POST();
        __builtin_amdgcn_s_barrier();

        LOAD_B(1, 1, bf1);
        if (nl) STAGE_A(0, 1, k2);
        SYNC_PRE(); MFMA_Q(0, 1, bf1); SYNC_POST();
        __builtin_amdgcn_s_barrier();

        LOAD_A(1, 1);
        if (nl) STAGE_A(1, 0, k3);
        SYNC_PRE(); MFMA_Q(1, 0, bf0); SYNC_POST();
        __builtin_amdgcn_s_barrier();

        if (nl) STAGE_B(1, 0, k3);
        SYNC_PRE(); MFMA_Q(1, 1, bf1); SYNC_POST();
        if (nl) { asm volatile("s_waitcnt vmcnt(4)" ::: "memory"); }   // K2
        __builtin_amdgcn_s_barrier();
    }

    // epilogue: C/D layout col = lane&15, row = quad*4 + r (m89-verified)
#pragma unroll
    for (int qa = 0; qa < 2; ++qa)
#pragma unroll
        for (int qb = 0; qb < 2; ++qb)
#pragma unroll
            for (int mf = 0; mf < 4; ++mf)
#pragma unroll
                for (int nf = 0; nf < 2; ++nf) {
                    const int row0 = rowA0 + qa * 128 + wm64 + mf * 16 + quad * 4;
                    float* cp = C + (size_t)row0 * COUT
                                  + rowB0 + qb * 128 + wn32 + nf * 16 + l16;
#pragma unroll
                    for (int r = 0; r < 4; ++r)
                        cp[(size_t)r * COUT] = acc[qa][qb][mf][nf][r];
                }
}

extern "C" void kernel_launch(void* const* d_in, const int* in_sizes, int n_in,
                              void* d_out, int out_size, void* d_ws, size_t ws_size,
                              hipStream_t stream) {
    const float* x    = (const float*)d_in[0];   // [M, CIN] fp32
    const float* vals = (const float*)d_in[1];   // [nnz] fp32
    const int*   idx  = (const int*)d_in[2];     // [2, nnz] int32

    float* out = (float*)d_out;                  // [M, COUT] fp32

    int nnz = in_sizes[2] / 2;
    int M   = in_sizes[0] / CIN;

    const size_t wf_bytes = (size_t)COUT * CIN * sizeof(float);          // 4 MB
    const size_t wb_bytes = (size_t)COUT * CIN * sizeof(unsigned short); // 2 MB

    float*          Wf = (float*)d_ws;
    unsigned short* Wb = (unsigned short*)((char*)d_ws + wf_bytes);
    unsigned short* Xb = (unsigned short*)((char*)d_ws + wf_bytes + wb_bytes);

    const int* rowsP = idx;
    const int* colsP = idx + nnz;

    // One cooperative launch: [zero+cvt_x] -> sync -> scatter -> sync ->
    // cvt_W -> sync -> gemm.  Grid (M/256)*(COUT/256) = 256 blocks = 1/CU
    // (128 KiB LDS), exactly co-resident.
    void* args[] = {
        (void*)&x, (void*)&vals, (void*)&rowsP, (void*)&colsP,
        (void*)&Wf, (void*)&Wb, (void*)&Xb, (void*)&out,
        (void*)&M, (void*)&nnz
    };
    const unsigned nblk = (unsigned)((M / 256) * (COUT / 256));
    hipLaunchCooperativeKernel((const void*)fused_all, dim3(nblk), dim3(512),
                               args, 0, stream);
}

// Round 4
// 181.003 us; speedup vs baseline: 1.3880x; 1.3880x over previous
//
#include <hip/hip_runtime.h>
#include <cstdint>
#include <cstddef>

// Problem constants: W is [COUT, CIN]; x is [4*4096, CIN]. All I/O fp32.
#define CIN  1024
#define COUT 1024

typedef __attribute__((ext_vector_type(8))) short bf16x8;
typedef __attribute__((ext_vector_type(4))) float f32x4;

// ---------- fp32 -> bf16 (round-to-nearest-even) ----------
__device__ __forceinline__ unsigned short f2bf(float f) {
    union { float f; unsigned int i; } v;
    v.f = f;
    unsigned int u = v.i;
    u += 0x7FFFu + ((u >> 16) & 1u);
    return (unsigned short)(u >> 16);
}

// ---------- kernel 1: zero the fp32 W accumulation buffer (1M floats) ----------
__global__ void zero_f32(float4* __restrict__ p) {
    p[blockIdx.x * 256 + threadIdx.x] = float4{0.f, 0.f, 0.f, 0.f};
}

// ---------- kernel 2: scatter-add fp32 COO values into dense fp32 W ----------
__global__ void scatter_add(const float* __restrict__ vals,
                            const int* __restrict__ rows,
                            const int* __restrict__ cols,
                            float* __restrict__ W, int nnz) {
    int i = blockIdx.x * 256 + threadIdx.x;
    if (i < nnz) {
        atomicAdd(W + (size_t)rows[i] * CIN + cols[i], vals[i]);
    }
}

// ---------- kernel 3: fp32 -> bf16 bulk convert (W only now) ----------
__global__ void cvt_bf16_bulk(const float* __restrict__ src, unsigned short* __restrict__ dst) {
    size_t i = ((size_t)blockIdx.x * 256 + threadIdx.x) * 8;
    float4 v0 = *(const float4*)(src + i);
    float4 v1 = *(const float4*)(src + i + 4);
    union { bf16x8 v; unsigned short u[8]; } w;
    w.u[0] = f2bf(v0.x); w.u[1] = f2bf(v0.y); w.u[2] = f2bf(v0.z); w.u[3] = f2bf(v0.w);
    w.u[4] = f2bf(v1.x); w.u[5] = f2bf(v1.y); w.u[6] = f2bf(v1.z); w.u[7] = f2bf(v1.w);
    *(bf16x8*)(dst + i) = w.v;
}

// ---------- kernel 4: 256x256 8-phase GEMM with fused fp32->bf16 A-staging ----
// C[M,N] = A[M,K](FP32, converted in-staging) * B[N,K](bf16)^T -> fp32.
// 512 thr = 8 waves (2Mx4N), BK=64, LDS 128 KiB. Per K-tile: 4 quadrant
// phases (A0B0)(A0B1)(A1B0)(A1B1), 16 MFMA each; frag persistence: af 2
// phases, bf0/bf1 whole K-tile (24 ds_read_b128 / K-tile / wave).
//
// A-staging (replaces cvt_x kernel; T14 issue-early/write-late):
//   issue 4x global_load_dwordx4 fp32 pre-bar at p1/p3/p5/p7; cvt(f2bf) +
//   2x ds_write_b128 at the START of p2/p4/p6/p8. Compiler inserts the
//   vmcnt wait at the cvt (~1 phase of latency hiding); FIFO vmem retire
//   means each cvt also drains all OLDER B gloads. ds_writes complete at
//   the writer's post-bar lgkmcnt(0), i.e. before its phase-end barrier ->
//   visible to consumers >=2 barriers later.
//   placements (deadline = first consuming phase):
//     p1->p2: buf1.A1(k1)  [read p7]      p3->p4: buf0.A0(k2) [read p1']
//     p5->p6: buf0.A1(k2)  [read p3']     p7->p8: buf1.A0(k3) [read p5']
//   WAR: each write-phase strictly follows the region's last-read phase.
// B-staging (gload_lds from Wb) and checkpoints unchanged: B1odd@p1,
//   B0even@p3, B1even@p5, B0odd'@p7; K1 vmcnt(2)@p4 (vmcnt(0) at i=7 --
//   REQUIRED there to publish buf1.B1 since p4 has no cvt), K2 vmcnt(2)@p8.
// LDS swizzle unchanged (0 conflicts): chunk slot = chunk ^ (row&7), applied
// on the global source for both A (fp32 chunk = 2 float4) and B, and on the
// chunk index of fragment reads.

#define GLD16(SRC_, DST_)                                                     \
  __builtin_amdgcn_global_load_lds(                                           \
      (const __attribute__((address_space(1))) void*)(SRC_),                  \
      (__attribute__((address_space(3))) void*)(DST_), 16, 0, 0)

#define STAGE_B(BUF_, HALF_, KT_) do {                                        \
    GLD16(pb + (size_t)((HALF_) * 128)      * CIN + (size_t)(KT_) * 64,       \
          Bs + (BUF_) * 16384 + ((HALF_) * 128) * 64 + tid8);                 \
    GLD16(pb + (size_t)((HALF_) * 128 + 64) * CIN + (size_t)(KT_) * 64,       \
          Bs + (BUF_) * 16384 + ((HALF_) * 128 + 64) * 64 + tid8);            \
  } while (0)

// A: issue 4 fp32 float4 loads (2 per 64-row sub-half) into ar0..ar3.
#define A_ISSUE(HALF_, KT_) do {                                              \
    const float* s0_ = pxa + (size_t)((HALF_) * 128) * CIN + (size_t)(KT_) * 64; \
    const float* s1_ = s0_ + (size_t)64 * CIN;                                \
    ar0 = *(const float4*)s0_;  ar1 = *(const float4*)(s0_ + 4);              \
    ar2 = *(const float4*)s1_;  ar3 = *(const float4*)(s1_ + 4);              \
  } while (0)

// A: cvt held fp32 -> bf16, ds_write to the linear gload_lds-equivalent slots.
#define A_WRITE(BUF_, HALF_) do {                                             \
    union { bf16x8 v; unsigned short u[8]; } w0_, w1_;                        \
    w0_.u[0] = f2bf(ar0.x); w0_.u[1] = f2bf(ar0.y);                           \
    w0_.u[2] = f2bf(ar0.z); w0_.u[3] = f2bf(ar0.w);                           \
    w0_.u[4] = f2bf(ar1.x); w0_.u[5] = f2bf(ar1.y);                           \
    w0_.u[6] = f2bf(ar1.z); w0_.u[7] = f2bf(ar1.w);                           \
    w1_.u[0] = f2bf(ar2.x); w1_.u[1] = f2bf(ar2.y);                           \
    w1_.u[2] = f2bf(ar2.z); w1_.u[3] = f2bf(ar2.w);                           \
    w1_.u[4] = f2bf(ar3.x); w1_.u[5] = f2bf(ar3.y);                           \
    w1_.u[6] = f2bf(ar3.z); w1_.u[7] = f2bf(ar3.w);                           \
    *(bf16x8*)(As + (BUF_) * 16384 + ((HALF_) * 128) * 64 + tid8)      = w0_.v; \
    *(bf16x8*)(As + (BUF_) * 16384 + ((HALF_) * 128 + 64) * 64 + tid8) = w1_.v; \
  } while (0)

#define LOAD_A(BUF_, QA_) do {                                                \
    const unsigned short* ab_ = As + (BUF_) * 16384 + ((QA_) * 128 + wm64) * 64; \
    _Pragma("unroll")                                                         \
    for (int ks_ = 0; ks_ < 2; ++ks_) {                                       \
      const int cx_ = ((ks_ * 4 + quad) ^ s7) * 8;                            \
      _Pragma("unroll")                                                       \
      for (int mf_ = 0; mf_ < 4; ++mf_)                                       \
        af[ks_][mf_] = *(const bf16x8*)(ab_ + (mf_ * 16 + l16) * 64 + cx_);   \
    }                                                                         \
  } while (0)

#define LOAD_B(BUF_, QB_, DST_) do {                                          \
    const unsigned short* bb_ = Bs + (BUF_) * 16384 + ((QB_) * 128 + wn32) * 64; \
    _Pragma("unroll")                                                         \
    for (int ks_ = 0; ks_ < 2; ++ks_) {                                       \
      const int cx_ = ((ks_ * 4 + quad) ^ s7) * 8;                            \
      _Pragma("unroll")                                                       \
      for (int nf_ = 0; nf_ < 2; ++nf_)                                       \
        DST_[ks_][nf_] = *(const bf16x8*)(bb_ + (nf_ * 16 + l16) * 64 + cx_); \
    }                                                                         \
  } while (0)

#define MFMA_Q(QA_, QB_, BF_)                                                 \
    _Pragma("unroll")                                                         \
    for (int ks_ = 0; ks_ < 2; ++ks_)                                         \
      _Pragma("unroll")                                                       \
      for (int mf_ = 0; mf_ < 4; ++mf_)                                       \
        _Pragma("unroll")                                                     \
        for (int nf_ = 0; nf_ < 2; ++nf_)                                     \
          acc[QA_][QB_][mf_][nf_] = __builtin_amdgcn_mfma_f32_16x16x32_bf16(  \
              af[ks_][mf_], BF_[ks_][nf_], acc[QA_][QB_][mf_][nf_], 0, 0, 0)

#define SYNC_PRE() do {                                                       \
    __builtin_amdgcn_s_barrier();                                             \
    asm volatile("s_waitcnt lgkmcnt(0)" ::: "memory");                        \
    __builtin_amdgcn_sched_barrier(0);                                        \
    __builtin_amdgcn_s_setprio(1);                                            \
  } while (0)

#define SYNC_POST() __builtin_amdgcn_s_setprio(0)

__global__ __launch_bounds__(512, 2) void gemm_8ph_fused(
    const float* __restrict__ X,            // [M, K] fp32 (A operand)
    const unsigned short* __restrict__ B,   // [N, K] bf16
    float* __restrict__ C,                  // [M, N] fp32
    int M) {
    (void)M;
    constexpr int K = CIN;

    __shared__ __align__(16) unsigned short As[2 * 16384];  // 2 x [256][64]
    __shared__ __align__(16) unsigned short Bs[2 * 16384];

    const int tid  = threadIdx.x;
    const int lane = tid & 63;
    const int w    = tid >> 6;
    const int quad = lane >> 4;
    const int l16  = lane & 15;
    const int s7   = l16 & 7;
    const int wm64 = (w >> 2) * 64;
    const int wn32 = (w & 3) * 32;

    const int rowA0 = blockIdx.x * 256;
    const int rowB0 = blockIdx.y * 256;

    // Staging maps. Source-side swizzle: thread (row=tid>>3, slot=tid&7)
    // fetches data-chunk slot^(row&7); LDS dst linear = base + tid*16B.
    const int stg_row = tid >> 3;
    const int c_data  = (tid & 7) ^ (stg_row & 7);
    const int tid8    = tid * 8;
    const float* pxa          = X + (size_t)(rowA0 + stg_row) * K + c_data * 8;
    const unsigned short* pb  = B + (size_t)(rowB0 + stg_row) * K + c_data * 8;

    f32x4 acc[2][2][4][2] = {};
    float4 ar0, ar1, ar2, ar3;             // in-flight fp32 A half-tile

    // ---- prologue: t0.B, then A chains (t0.A0, t0.A1, t1.A0), then t1.B0 ----
    STAGE_B(0, 0, 0); STAGE_B(0, 1, 0);
    A_ISSUE(0, 0);  A_WRITE(0, 0);         // cvt auto-waits; drains older B
    A_ISSUE(1, 0);  A_WRITE(0, 1);
    A_ISSUE(0, 1);  A_WRITE(1, 0);         // drains t0.B entirely
    STAGE_B(1, 0, 1);
    asm volatile("s_waitcnt lgkmcnt(0)" ::: "memory");   // ds_writes done
    __builtin_amdgcn_s_barrier();          // 2 vmem outstanding (t1.B0)

#pragma unroll 1
    for (int i = 0; i < 8; ++i) {          // 16 K-tiles of 64, 2 per iteration
        const int  k1 = 2 * i + 1;
        const int  k2 = 2 * i + 2;
        const int  k3 = 2 * i + 3;
        const bool nl = (i < 7);

        bf16x8 af[2][4];                   // A-frags, reused 2 phases
        bf16x8 bf0[2][2], bf1[2][2];       // B-frags, persist whole K-tile

        // ---- even tile (buf0) ----
        // p1
        LOAD_A(0, 0); LOAD_B(0, 0, bf0);
        A_ISSUE(1, k1);                    // buf1.A1
        STAGE_B(1, 1, k1);
        SYNC_PRE(); MFMA_Q(0, 0, bf0); SYNC_POST();
        __builtin_amdgcn_s_barrier();
        // p2
        A_WRITE(1, 1);                     // cvt+write buf1.A1
        LOAD_B(0, 1, bf1);
        SYNC_PRE(); MFMA_Q(0, 1, bf1); SYNC_POST();
        __builtin_amdgcn_s_barrier();
        // p3
        LOAD_A(0, 1);
        if (nl) { A_ISSUE(0, k2); STAGE_B(0, 0, k2); }
        SYNC_PRE(); MFMA_Q(1, 0, bf0); SYNC_POST();
        __builtin_amdgcn_s_barrier();
        // p4
        if (nl) A_WRITE(0, 0);             // cvt+write buf0.A0
        SYNC_PRE(); MFMA_Q(1, 1, bf1); SYNC_POST();
        if (nl) { asm volatile("s_waitcnt vmcnt(2)" ::: "memory"); }   // K1
        else    { asm volatile("s_waitcnt vmcnt(0)" ::: "memory"); }   // publish buf1.B1
        __builtin_amdgcn_s_barrier();

        // ---- odd tile (buf1) ----
        // p5
        LOAD_A(1, 0); LOAD_B(1, 0, bf0);
        if (nl) { A_ISSUE(1, k2); STAGE_B(0, 1, k2); }
        SYNC_PRE(); MFMA_Q(0, 0, bf0); SYNC_POST();
        __builtin_amdgcn_s_barrier();
        // p6
        if (nl) A_WRITE(0, 1);             // cvt+write buf0.A1
        LOAD_B(1, 1, bf1);
        SYNC_PRE(); MFMA_Q(0, 1, bf1); SYNC_POST();
        __builtin_amdgcn_s_barrier();
        // p7
        LOAD_A(1, 1);
        if (nl) { A_ISSUE(0, k3); STAGE_B(1, 0, k3); }
        SYNC_PRE(); MFMA_Q(1, 0, bf0); SYNC_POST();
        __builtin_amdgcn_s_barrier();
        // p8
        if (nl) A_WRITE(1, 0);             // cvt+write buf1.A0
        SYNC_PRE(); MFMA_Q(1, 1, bf1); SYNC_POST();
        if (nl) { asm volatile("s_waitcnt vmcnt(2)" ::: "memory"); }   // K2
        __builtin_amdgcn_s_barrier();
    }

    // ---- epilogue: C/D layout col = lane&15, row = quad*4 + r (m89-verified) ----
#pragma unroll
    for (int qa = 0; qa < 2; ++qa)
#pragma unroll
        for (int qb = 0; qb < 2; ++qb)
#pragma unroll
            for (int mf = 0; mf < 4; ++mf)
#pragma unroll
                for (int nf = 0; nf < 2; ++nf) {
                    const int row0 = rowA0 + qa * 128 + wm64 + mf * 16 + quad * 4;
                    float* cp = C + (size_t)row0 * COUT
                                  + rowB0 + qb * 128 + wn32 + nf * 16 + l16;
#pragma unroll
                    for (int r = 0; r < 4; ++r)
                        cp[(size_t)r * COUT] = acc[qa][qb][mf][nf][r];
                }
}

extern "C" void kernel_launch(void* const* d_in, const int* in_sizes, int n_in,
                              void* d_out, int out_size, void* d_ws, size_t ws_size,
                              hipStream_t stream) {
    const float* x    = (const float*)d_in[0];   // [M, CIN] fp32
    const float* vals = (const float*)d_in[1];   // [nnz] fp32
    const int*   idx  = (const int*)d_in[2];     // [2, nnz] int32

    float* out = (float*)d_out;                  // [M, COUT] fp32

    const int nnz = in_sizes[2] / 2;
    const int M   = in_sizes[0] / CIN;

    const size_t wf_bytes = (size_t)COUT * CIN * sizeof(float);          // 4 MB

    float*          Wf = (float*)d_ws;
    unsigned short* Wb = (unsigned short*)((char*)d_ws + wf_bytes);

    // 1) zero fp32 W (ws is poisoned 0xAA before every call)
    zero_f32<<<dim3(COUT * CIN / (256 * 4)), dim3(256), 0, stream>>>((float4*)Wf);
    // 2) scatter-add duplicates like coalesce()
    scatter_add<<<dim3((nnz + 255) / 256), dim3(256), 0, stream>>>(vals, idx, idx + nnz, Wf, nnz);
    // 3) W -> bf16
    cvt_bf16_bulk<<<dim3(COUT * CIN / (256 * 8)), dim3(256), 0, stream>>>(Wf, Wb);
    // 4) GEMM with fused x-conversion: out = x @ W^T.  grid (64,4) = 256 blocks.
    gemm_8ph_fused<<<dim3(M / 256, COUT / 256), dim3(512), 0, stream>>>(x, Wb, out, M);
}

// Round 5
// 161.591 us; speedup vs baseline: 1.5548x; 1.1201x over previous
//
#include <hip/hip_runtime.h>
#include <cstdint>
#include <cstddef>

// Problem constants: W is [COUT, CIN]; x is [4*4096, CIN]. All I/O fp32.
#define CIN  1024
#define COUT 1024

typedef __attribute__((ext_vector_type(8))) short bf16x8;
typedef __attribute__((ext_vector_type(4))) float f32x4;

// ---------- fp32 -> bf16 (round-to-nearest-even) ----------
__device__ __forceinline__ unsigned short f2bf(float f) {
    union { float f; unsigned int i; } v;
    v.f = f;
    unsigned int u = v.i;
    u += 0x7FFFu + ((u >> 16) & 1u);
    return (unsigned short)(u >> 16);
}

// ---------- kernel 1: zero the fp32 W accumulation buffer (1M floats) ----------
__global__ void zero_f32(float4* __restrict__ p) {
    p[blockIdx.x * 256 + threadIdx.x] = float4{0.f, 0.f, 0.f, 0.f};
}

// ---------- kernel 2: scatter-add fp32 COO values into dense fp32 W ----------
__global__ void scatter_add(const float* __restrict__ vals,
                            const int* __restrict__ rows,
                            const int* __restrict__ cols,
                            float* __restrict__ W, int nnz) {
    int i = blockIdx.x * 256 + threadIdx.x;
    if (i < nnz) {
        atomicAdd(W + (size_t)rows[i] * CIN + cols[i], vals[i]);
    }
}

// ---------- kernel 3: fp32 -> bf16 bulk convert (used for W and for x) ----------
// NOTE (round-4 lesson): cvt_x is NOT overhead — Xb is a 2x compression of a
// 4x-redundant A-stream (slab shared by 4 by-blocks; per-XCD working set
// exceeds L2, so redundancy is served by L3). Fusing the cvt into the GEMM
// doubled L3 traffic and cost +40us. Keep the separate pass.
__global__ void cvt_bf16_bulk(const float* __restrict__ src, unsigned short* __restrict__ dst) {
    size_t i = ((size_t)blockIdx.x * 256 + threadIdx.x) * 8;
    float4 v0 = *(const float4*)(src + i);
    float4 v1 = *(const float4*)(src + i + 4);
    union { bf16x8 v; unsigned short u[8]; } w;
    w.u[0] = f2bf(v0.x); w.u[1] = f2bf(v0.y); w.u[2] = f2bf(v0.z); w.u[3] = f2bf(v0.w);
    w.u[4] = f2bf(v1.x); w.u[5] = f2bf(v1.y); w.u[6] = f2bf(v1.z); w.u[7] = f2bf(v1.w);
    *(bf16x8*)(dst + i) = w.v;
}

// ---------- kernel 4: 256x256 GEMM, v3 = v2 schedule with merged phases ----------
// C[M,N] = A[M,K](bf16) * B[N,K](bf16)^T -> fp32.
// 512 thr = 8 waves (2Mx4N), BK=64, LDS 128 KiB (2 buf x [256][64] x {A,B}).
// v3: merge v2's phase pairs -> 4 phases per 2 K-tiles, 32 MFMA/phase.
// Rationale: round-2 counters (MfmaUtil 28, VALU 11, HBM 26%, conflicts 0)
// => sync-bound; ~515cyc/phase vs ~155cyc MFMA content. Halving the number
// of {barrier, lgkmcnt(0), setprio} rounds (128->64 barriers/block) attacks
// that overhead while keeping v2's staging/WAR/completion structure intact:
//   P12: reads {A0,B0,B1};   stages odd{B1,A1}(k1)
//   P34: reads {A1};         stages even{A0,B0}(k2);  K1: vmcnt(4)
//   P56: reads {A0,B0,B1};   stages even{B1,A1}(k2)
//   P78: reads {A1};         stages odd'{A0,B0}(k3);  K2: vmcnt(4)
// K1 completes the odd tile (4 younger loads remain), K2 the even tile.
// Last iter: P34/P56/P78 stages skipped, K1 = vmcnt(0) (publishes buf1).
// WAR: every staged region's last ds_read is in an earlier barrier-separated
// phase (oB1: prev P56; oA1: prev P78; eA0,eB0,eB1: this P12; eA1: this P34;
// o'A0,o'B0: this P56).
// LDS swizzle unchanged (0 conflicts measured): chunk slot = chunk ^ (row&7),
// applied on the GLOBAL source for global_load_lds (linear LDS dst) and on
// the chunk index of fragment ds_reads.

#define GLD16(SRC_, DST_)                                                     \
  __builtin_amdgcn_global_load_lds(                                           \
      (const __attribute__((address_space(1))) void*)(SRC_),                  \
      (__attribute__((address_space(3))) void*)(DST_), 16, 0, 0)

#define STAGE_A(BUF_, HALF_, KT_) do {                                        \
    GLD16(pa + (size_t)((HALF_) * 128)      * CIN + (size_t)(KT_) * 64,       \
          As + (BUF_) * 16384 + ((HALF_) * 128) * 64 + tid8);                 \
    GLD16(pa + (size_t)((HALF_) * 128 + 64) * CIN + (size_t)(KT_) * 64,       \
          As + (BUF_) * 16384 + ((HALF_) * 128 + 64) * 64 + tid8);            \
  } while (0)

#define STAGE_B(BUF_, HALF_, KT_) do {                                        \
    GLD16(pb + (size_t)((HALF_) * 128)      * CIN + (size_t)(KT_) * 64,       \
          Bs + (BUF_) * 16384 + ((HALF_) * 128) * 64 + tid8);                 \
    GLD16(pb + (size_t)((HALF_) * 128 + 64) * CIN + (size_t)(KT_) * 64,       \
          Bs + (BUF_) * 16384 + ((HALF_) * 128 + 64) * 64 + tid8);            \
  } while (0)

// Fragment loads (static indices only -> registers).
#define LOAD_A(BUF_, QA_) do {                                                \
    const unsigned short* ab_ = As + (BUF_) * 16384 + ((QA_) * 128 + wm64) * 64; \
    _Pragma("unroll")                                                         \
    for (int ks_ = 0; ks_ < 2; ++ks_) {                                       \
      const int cx_ = ((ks_ * 4 + quad) ^ s7) * 8;                            \
      _Pragma("unroll")                                                       \
      for (int mf_ = 0; mf_ < 4; ++mf_)                                       \
        af[ks_][mf_] = *(const bf16x8*)(ab_ + (mf_ * 16 + l16) * 64 + cx_);   \
    }                                                                         \
  } while (0)

#define LOAD_B(BUF_, QB_, DST_) do {                                          \
    const unsigned short* bb_ = Bs + (BUF_) * 16384 + ((QB_) * 128 + wn32) * 64; \
    _Pragma("unroll")                                                         \
    for (int ks_ = 0; ks_ < 2; ++ks_) {                                       \
      const int cx_ = ((ks_ * 4 + quad) ^ s7) * 8;                            \
      _Pragma("unroll")                                                       \
      for (int nf_ = 0; nf_ < 2; ++nf_)                                       \
        DST_[ks_][nf_] = *(const bf16x8*)(bb_ + (nf_ * 16 + l16) * 64 + cx_); \
    }                                                                         \
  } while (0)

#define MFMA_Q(QA_, QB_, BF_)                                                 \
    _Pragma("unroll")                                                         \
    for (int ks_ = 0; ks_ < 2; ++ks_)                                         \
      _Pragma("unroll")                                                       \
      for (int mf_ = 0; mf_ < 4; ++mf_)                                       \
        _Pragma("unroll")                                                     \
        for (int nf_ = 0; nf_ < 2; ++nf_)                                     \
          acc[QA_][QB_][mf_][nf_] = __builtin_amdgcn_mfma_f32_16x16x32_bf16(  \
              af[ks_][mf_], BF_[ks_][nf_], acc[QA_][QB_][mf_][nf_], 0, 0, 0)

#define SYNC_PRE() do {                                                       \
    __builtin_amdgcn_s_barrier();                                             \
    asm volatile("s_waitcnt lgkmcnt(0)" ::: "memory");                        \
    __builtin_amdgcn_sched_barrier(0);                                        \
    __builtin_amdgcn_s_setprio(1);                                            \
  } while (0)

#define SYNC_POST() __builtin_amdgcn_s_setprio(0)

__global__ __launch_bounds__(512, 2) void gemm_4ph(
    const unsigned short* __restrict__ A,   // [M, K] bf16
    const unsigned short* __restrict__ B,   // [N, K] bf16
    float* __restrict__ C,                  // [M, N] fp32
    int M) {
    (void)M;
    constexpr int K = CIN;

    __shared__ __align__(16) unsigned short As[2 * 16384];  // 2 x [256][64]
    __shared__ __align__(16) unsigned short Bs[2 * 16384];

    const int tid  = threadIdx.x;
    const int lane = tid & 63;
    const int w    = tid >> 6;
    const int quad = lane >> 4;
    const int l16  = lane & 15;
    const int s7   = l16 & 7;
    const int wm64 = (w >> 2) * 64;   // wave row offset within a 128x128 quadrant
    const int wn32 = (w & 3) * 32;    // wave col offset within a 128x128 quadrant

    const int rowA0 = blockIdx.x * 256;
    const int rowB0 = blockIdx.y * 256;

    // Staging map (source-side swizzle; LDS dest linear = base + tid*16B).
    const int stg_row = tid >> 3;
    const int c_data  = (tid & 7) ^ (stg_row & 7);
    const int tid8    = tid * 8;
    const unsigned short* pa = A + (size_t)(rowA0 + stg_row) * K + c_data * 8;
    const unsigned short* pb = B + (size_t)(rowB0 + stg_row) * K + c_data * 8;

    f32x4 acc[2][2][4][2] = {};

    // ---- prologue: tile0 -> buf0 (A0,B0,B1,A1), tile1 -> buf1 (A0,B0) ----
    STAGE_A(0, 0, 0); STAGE_B(0, 0, 0); STAGE_B(0, 1, 0); STAGE_A(0, 1, 0);
    STAGE_A(1, 0, 1); STAGE_B(1, 0, 1);
    asm volatile("s_waitcnt vmcnt(4)" ::: "memory");  // tile0 complete
    __builtin_amdgcn_s_barrier();

#pragma unroll 1
    for (int i = 0; i < 8; ++i) {          // 16 K-tiles of 64, 2 per iteration
        const int  k1 = 2 * i + 1;
        const int  k2 = 2 * i + 2;
        const int  k3 = 2 * i + 3;
        const bool nl = (i < 7);

        bf16x8 af[2][4];                   // A-frags, reused within a merged phase
        bf16x8 bf0[2][2], bf1[2][2];       // B-frags, persist whole K-tile

        // ---- P12: even tile (buf0), quadrants (0,0)+(0,1) ----
        LOAD_A(0, 0); LOAD_B(0, 0, bf0); LOAD_B(0, 1, bf1);
        STAGE_B(1, 1, k1); STAGE_A(1, 1, k1);
        SYNC_PRE(); MFMA_Q(0, 0, bf0); MFMA_Q(0, 1, bf1); SYNC_POST();
        __builtin_amdgcn_s_barrier();

        // ---- P34: even tile, quadrants (1,0)+(1,1) ----
        LOAD_A(0, 1);
        if (nl) { STAGE_A(0, 0, k2); STAGE_B(0, 0, k2); }
        SYNC_PRE(); MFMA_Q(1, 0, bf0); MFMA_Q(1, 1, bf1); SYNC_POST();
        if (nl) { asm volatile("s_waitcnt vmcnt(4)" ::: "memory"); }   // K1: odd tile ready
        else    { asm volatile("s_waitcnt vmcnt(0)" ::: "memory"); }   // publish buf1
        __builtin_amdgcn_s_barrier();

        // ---- P56: odd tile (buf1), quadrants (0,0)+(0,1) ----
        LOAD_A(1, 0); LOAD_B(1, 0, bf0); LOAD_B(1, 1, bf1);
        if (nl) { STAGE_B(0, 1, k2); STAGE_A(0, 1, k2); }
        SYNC_PRE(); MFMA_Q(0, 0, bf0); MFMA_Q(0, 1, bf1); SYNC_POST();
        __builtin_amdgcn_s_barrier();

        // ---- P78: odd tile, quadrants (1,0)+(1,1) ----
        LOAD_A(1, 1);
        if (nl) { STAGE_A(1, 0, k3); STAGE_B(1, 0, k3); }
        SYNC_PRE(); MFMA_Q(1, 0, bf0); MFMA_Q(1, 1, bf1); SYNC_POST();
        if (nl) { asm volatile("s_waitcnt vmcnt(4)" ::: "memory"); }   // K2: even tile ready
        __builtin_amdgcn_s_barrier();
    }

    // ---- epilogue: C/D layout col = lane&15, row = quad*4 + r (m89-verified) ----
#pragma unroll
    for (int qa = 0; qa < 2; ++qa)
#pragma unroll
        for (int qb = 0; qb < 2; ++qb)
#pragma unroll
            for (int mf = 0; mf < 4; ++mf)
#pragma unroll
                for (int nf = 0; nf < 2; ++nf) {
                    const int row0 = rowA0 + qa * 128 + wm64 + mf * 16 + quad * 4;
                    float* cp = C + (size_t)row0 * COUT
                                  + rowB0 + qb * 128 + wn32 + nf * 16 + l16;
#pragma unroll
                    for (int r = 0; r < 4; ++r)
                        cp[(size_t)r * COUT] = acc[qa][qb][mf][nf][r];
                }
}

extern "C" void kernel_launch(void* const* d_in, const int* in_sizes, int n_in,
                              void* d_out, int out_size, void* d_ws, size_t ws_size,
                              hipStream_t stream) {
    const float* x    = (const float*)d_in[0];   // [M, CIN] fp32
    const float* vals = (const float*)d_in[1];   // [nnz] fp32
    const int*   idx  = (const int*)d_in[2];     // [2, nnz] int32

    float* out = (float*)d_out;                  // [M, COUT] fp32

    const int nnz = in_sizes[2] / 2;
    const int M   = in_sizes[0] / CIN;

    const size_t wf_bytes = (size_t)COUT * CIN * sizeof(float);          // 4 MB
    const size_t wb_bytes = (size_t)COUT * CIN * sizeof(unsigned short); // 2 MB

    float*          Wf = (float*)d_ws;
    unsigned short* Wb = (unsigned short*)((char*)d_ws + wf_bytes);
    unsigned short* Xb = (unsigned short*)((char*)d_ws + wf_bytes + wb_bytes);

    // 1) zero fp32 W (ws is poisoned 0xAA before every call)
    zero_f32<<<dim3(COUT * CIN / (256 * 4)), dim3(256), 0, stream>>>((float4*)Wf);
    // 2) scatter-add duplicates like coalesce()
    scatter_add<<<dim3((nnz + 255) / 256), dim3(256), 0, stream>>>(vals, idx, idx + nnz, Wf, nnz);
    // 3) W -> bf16
    cvt_bf16_bulk<<<dim3(COUT * CIN / (256 * 8)), dim3(256), 0, stream>>>(Wf, Wb);
    // 4) x -> bf16 (compression pass; see note on kernel 3)
    cvt_bf16_bulk<<<dim3((unsigned)((size_t)M * CIN / (256 * 8))), dim3(256), 0, stream>>>(x, Xb);
    // 5) merged-phase GEMM: out = x @ W^T.  grid (64,4) = 256 blocks = 1/CU.
    gemm_4ph<<<dim3(M / 256, COUT / 256), dim3(512), 0, stream>>>(Xb, Wb, out, M);
}